// Round 10
// baseline (122.052 us; speedup 1.0000x reference)
//
#include <hip/hip_runtime.h>

// Problem constants (from reference setup_inputs)
#define BZ 4
#define H 192
#define W 640
#define PIX (H * W)            // 122880 pixels per batch
#define MAXINS 200
#define CAND 16
#define CE 36                  // ch*cw
#define CE4 9                  // float4 groups per pixel
#define BATCH_FLOATS (MAXINS * CE)          // 7200 floats per batch
#define BATCH_F4     (BATCH_FLOATS / 4)     // 1800 float4 per batch
#define COMP_FLOATS (BZ * BATCH_FLOATS)     // 28800 floats
#define COMP_BYTES  (COMP_FLOATS * 4)       // 115200 bytes
#define LSTRIDE 37                          // padded LDS row (bank spread)
#define BPB 192                             // blocks per batch for compress
#define NBLK (BZ * BPB)                     // 768 compress blocks (~3/CU)
#define PART_BYTES ((size_t)NBLK * BATCH_FLOATS * 4)   // 22.1 MB

// Native LDS fp32 atomic add (ds_add_f32). Plain atomicAdd(float*) is
// CAS-expanded by hipcc without -munsafe-fp-atomics (~210 cyc/wave-instr
// measured r9); unsafeAtomicAdd carries the no-fine-grained metadata that
// lets the backend select the native instruction.
__device__ __forceinline__ void lds_fadd(float* p, float v) {
    unsafeAtomicAdd(p, v);
}

// =================== Path A: private non-atomic partials =================
// Replay-safe by construction: every ws byte this path reads is overwritten
// by plain stores earlier in the same call. No global atomics, no zeroing.

__global__ void compress_priv_kernel(const int* __restrict__ inst,
                                     const float4* __restrict__ compsrc,
                                     float4* __restrict__ partials) {
    __shared__ float lcomp[MAXINS * LSTRIDE];   // 29.6 KB, padded
    for (int i = threadIdx.x; i < MAXINS * LSTRIDE; i += blockDim.x) lcomp[i] = 0.f;
    __syncthreads();

    const int b   = blockIdx.x / BPB;
    const int blk = blockIdx.x % BPB;
    const unsigned base = (unsigned)b * PIX * CE4;

    for (unsigned t = blk * blockDim.x + threadIdx.x; t < PIX * CE4;
         t += BPB * blockDim.x) {
        const unsigned pix = t / CE4;
        const unsigned e4  = t - pix * CE4;
        const int m = inst[b * PIX + pix];      // 9 adjacent lanes share (L1 bcast)
        float4 v = compsrc[base + t];           // fully coalesced 16B/lane
        float* dst = lcomp + m * LSTRIDE + e4 * 4;
        lds_fadd(dst + 0, v.x);                 // native ds_add_f32
        lds_fadd(dst + 1, v.y);
        lds_fadd(dst + 2, v.z);
        lds_fadd(dst + 3, v.w);
    }
    __syncthreads();

    // Store the FULL private partial (zeros included) -> every byte written.
    float4* p = partials + (size_t)blockIdx.x * BATCH_F4;
    for (int j = threadIdx.x; j < BATCH_F4; j += blockDim.x) {
        const int f = j * 4;                    // float index; CE%4==0 -> no row cross
        const int m = f / CE;
        const int k = f - m * CE;
        const float* ls = lcomp + m * LSTRIDE + k;
        p[j] = make_float4(ls[0], ls[1], ls[2], ls[3]);   // coalesced store
    }
}

// comp[t4] = sel gather + sum over the BPB partial slots of batch b
__global__ void reduce_priv_kernel(const float4* __restrict__ partials,
                                   const int* __restrict__ batchidx,
                                   const float4* __restrict__ selsrc,
                                   float4* __restrict__ comp) {
    const int t = blockIdx.x * blockDim.x + threadIdx.x;   // over 7200 float4
    if (t >= COMP_FLOATS / 4) return;
    const int e4 = t % CE4;
    const int bm = t / CE4;                    // b*MAXINS + m
    const int b  = t / BATCH_F4;
    const int j  = t - b * BATCH_F4;           // == (bm%MAXINS)*9 + e4
    const int c  = batchidx[bm];
    float4 acc = selsrc[((size_t)bm * CAND + c) * CE4 + e4];
    const float4* p = partials + (size_t)b * BPB * BATCH_F4 + j;
    #pragma unroll 8
    for (int s = 0; s < BPB; ++s) {
        float4 v = p[(size_t)s * BATCH_F4];    // independent loads -> ILP
        acc.x += v.x; acc.y += v.y; acc.z += v.z; acc.w += v.w;
    }
    comp[t] = acc;
}

// ============ Path B: shadow-atomic (device-scope hardened) ==============

__global__ void zero_shadows_kernel(float* __restrict__ p, int n) {
    for (int t = blockIdx.x * blockDim.x + threadIdx.x; t < n;
         t += gridDim.x * blockDim.x)
        __hip_atomic_store(p + t, 0.f, __ATOMIC_RELAXED, __HIP_MEMORY_SCOPE_AGENT);
}

__global__ void compress_shadow_kernel(const int* __restrict__ inst,
                                       const float4* __restrict__ compsrc,
                                       float* __restrict__ shadows, int R) {
    __shared__ float lcomp[MAXINS * LSTRIDE];
    for (int i = threadIdx.x; i < MAXINS * LSTRIDE; i += blockDim.x) lcomp[i] = 0.f;
    __syncthreads();

    const int b   = blockIdx.x / BPB;
    const int blk = blockIdx.x % BPB;
    const unsigned base = (unsigned)b * PIX * CE4;

    for (unsigned t = blk * blockDim.x + threadIdx.x; t < PIX * CE4;
         t += BPB * blockDim.x) {
        const unsigned pix = t / CE4;
        const unsigned e4  = t - pix * CE4;
        const int m = inst[b * PIX + pix];
        float4 v = compsrc[base + t];
        float* dst = lcomp + m * LSTRIDE + e4 * 4;
        lds_fadd(dst + 0, v.x);
        lds_fadd(dst + 1, v.y);
        lds_fadd(dst + 2, v.z);
        lds_fadd(dst + 3, v.w);
    }
    __syncthreads();

    float* sh = shadows + (size_t)(blockIdx.x % R) * COMP_FLOATS
                        + (size_t)b * BATCH_FLOATS;
    for (int i = threadIdx.x; i < BATCH_FLOATS; i += blockDim.x) {
        const int m = i / CE;
        const int k = i - m * CE;
        atomicAdd(sh + i, lcomp[m * LSTRIDE + k]);
    }
}

__global__ void reduce_shadow_kernel(const float* __restrict__ shadows,
                                     const int* __restrict__ batchidx,
                                     const float* __restrict__ selsrc,
                                     float* __restrict__ comp, int R) {
    const int i = blockIdx.x * blockDim.x + threadIdx.x;   // over 28800 floats
    if (i >= COMP_FLOATS) return;
    const int k  = i % CE;
    const int bm = i / CE;
    const int c  = batchidx[bm];
    float acc = selsrc[((size_t)bm * CAND + c) * CE + k];
    for (int r = 0; r < R; ++r)
        acc += __hip_atomic_load(shadows + (size_t)r * COMP_FLOATS + i,
                                 __ATOMIC_RELAXED, __HIP_MEMORY_SCOPE_AGENT);
    comp[i] = acc;
}

// ============ Path C: direct atomics (minimal ws) ========================

__global__ void init_sel_kernel(const int* __restrict__ batchidx,
                                const float4* __restrict__ selsrc,
                                float4* __restrict__ comp) {
    unsigned t = blockIdx.x * blockDim.x + threadIdx.x;   // 7200
    if (t >= BZ * MAXINS * CE4) return;
    unsigned e4 = t % CE4;
    unsigned bm = t / CE4;
    int c = batchidx[bm];
    comp[bm * CE4 + e4] = selsrc[(bm * CAND + (unsigned)c) * CE4 + e4];
}

__global__ void compress_direct_kernel(const int* __restrict__ inst,
                                       const float4* __restrict__ compsrc,
                                       float* __restrict__ comp) {
    const unsigned total = BZ * PIX * CE4;
    for (unsigned t = blockIdx.x * blockDim.x + threadIdx.x; t < total;
         t += gridDim.x * blockDim.x) {
        unsigned e4 = t % CE4;
        unsigned pix = t / CE4;
        unsigned b = pix / PIX;
        int m = inst[pix];
        float4 v = compsrc[t];
        float* dst = comp + ((unsigned)(b * MAXINS + m)) * CE + e4 * 4;
        atomicAdd(dst + 0, v.x);
        atomicAdd(dst + 1, v.y);
        atomicAdd(dst + 2, v.z);
        atomicAdd(dst + 3, v.w);
    }
}

// ============ K3: inflate ================================================

__global__ void inflate_kernel(const int* __restrict__ inst,
                               const float4* __restrict__ comp,
                               float4* __restrict__ out) {
    const unsigned total = BZ * PIX * CE4;
    for (unsigned t = blockIdx.x * blockDim.x + threadIdx.x; t < total;
         t += gridDim.x * blockDim.x) {
        unsigned e4 = t % CE4;
        unsigned pix = t / CE4;
        unsigned b = pix / PIX;
        int m = inst[pix];
        out[t] = comp[((unsigned)(b * MAXINS + m)) * CE4 + e4];  // L2-hot gather
    }
}

extern "C" void kernel_launch(void* const* d_in, const int* in_sizes, int n_in,
                              void* d_out, int out_size, void* d_ws, size_t ws_size,
                              hipStream_t stream) {
    const int*    inst     = (const int*)d_in[0];      // (BZ,1,H,W) int32
    const float*  compsrc  = (const float*)d_in[1];    // (BZ,H,W,6,6) f32
    const int*    batchidx = (const int*)d_in[2];      // (BZ,MAXINS) int32
    const float*  selsrc   = (const float*)d_in[3];    // (BZ,MAXINS,CAND,6,6) f32
    float*        out      = (float*)d_out;            // (BZ,H,W,6,6) f32
    float*        comp     = (float*)d_ws;             // final comp: 115.2 KB @ ws[0]

    if (ws_size >= (size_t)COMP_BYTES + PART_BYTES) {
        // --- Path A: private partials, no global atomics, no zeroing ---
        float4* partials = (float4*)(comp + COMP_FLOATS);
        compress_priv_kernel<<<NBLK, 256, 0, stream>>>(inst, (const float4*)compsrc,
                                                       partials);
        reduce_priv_kernel<<<(COMP_FLOATS / 4 + 255) / 256, 256, 0, stream>>>(
            partials, batchidx, (const float4*)selsrc, (float4*)comp);
    } else if (ws_size >= 2 * (size_t)COMP_BYTES) {
        // --- Path B: shadow atomics, device-scope-coherent zero/read ---
        long r_avail = (long)(ws_size / COMP_BYTES) - 1;
        int R = (int)(r_avail > 16 ? 16 : r_avail);
        float* shadows = comp + COMP_FLOATS;
        int n = R * COMP_FLOATS;
        zero_shadows_kernel<<<(n + 255) / 256, 256, 0, stream>>>(shadows, n);
        compress_shadow_kernel<<<NBLK, 256, 0, stream>>>(inst, (const float4*)compsrc,
                                                         shadows, R);
        reduce_shadow_kernel<<<(COMP_FLOATS + 255) / 256, 256, 0, stream>>>(
            shadows, batchidx, selsrc, comp, R);
    } else {
        // --- Path C: direct atomics into comp ---
        const int total = BZ * MAXINS * CE4;
        init_sel_kernel<<<(total + 255) / 256, 256, 0, stream>>>(
            batchidx, (const float4*)selsrc, (float4*)comp);
        compress_direct_kernel<<<2048, 256, 0, stream>>>(inst, (const float4*)compsrc,
                                                         comp);
    }

    // K3: inflate comp back to per-pixel output
    inflate_kernel<<<2048, 256, 0, stream>>>(inst, (const float4*)comp, (float4*)out);
}

// Round 11
// 56.602 us; speedup vs baseline: 2.1563x; 2.1563x over previous
//
#include <hip/hip_runtime.h>

// Problem constants (from reference setup_inputs)
#define BZ 4
#define H 192
#define W 640
#define PIX (H * W)            // 122880 pixels per batch
#define MAXINS 200
#define CAND 16
#define CE 36                  // ch*cw
#define CE4 9                  // float4 groups per pixel
#define BATCH_FLOATS (MAXINS * CE)          // 7200 floats per batch
#define BATCH_F4     (BATCH_FLOATS / 4)     // 1800 float4 per batch
#define COMP_FLOATS (BZ * BATCH_FLOATS)     // 28800 floats
#define COMP_BYTES  (COMP_FLOATS * 4)       // 115200 bytes
#define BPB 192                             // blocks per batch
#define NBLK (BZ * BPB)                     // 768 compress blocks
#define STRIPE (PIX / BPB)                  // 640 contiguous pixels per block
#define ITEMS 8                             // ceil(1800/256) per-thread items
#define PART_BYTES ((size_t)NBLK * BATCH_FLOATS * 4)   // 22.1 MB

// ============ compress: block-local counting sort, NO fp atomics =========
// r6/r9/r10 showed the 17.7M LDS fp-atomic lane-ops are the wall (~95us
// invariant under coalescing/occupancy/atomic-flavor changes). This kernel
// replaces them with 0.5M int LDS atomics + register accumulation.

__global__ __launch_bounds__(256) void compress_sort_kernel(
        const int* __restrict__ inst,
        const float4* __restrict__ compsrc,
        float4* __restrict__ partials) {
    __shared__ unsigned char  mloc[STRIPE];     // per-pixel m (cached)
    __shared__ unsigned short sorted[STRIPE];   // local pixel ids, grouped by m
    __shared__ int cnt[MAXINS];
    __shared__ int off[MAXINS + 1];
    __shared__ int off_run[MAXINS];
    __shared__ int tmp[256];

    const int b    = blockIdx.x / BPB;
    const int blk  = blockIdx.x % BPB;
    const int tid  = threadIdx.x;
    const int pix0 = blk * STRIPE;

    if (tid < MAXINS) cnt[tid] = 0;
    __syncthreads();

    // ---- count pass: 640 int LDS atomics, cache m ----
    for (int p = tid; p < STRIPE; p += 256) {
        int m = inst[b * PIX + pix0 + p];       // coalesced
        mloc[p] = (unsigned char)m;
        atomicAdd(&cnt[m], 1);                  // ds_add_u32
    }
    __syncthreads();

    // ---- exclusive scan cnt -> off (Hillis-Steele, 256-padded) ----
    int c = (tid < MAXINS) ? cnt[tid] : 0;
    tmp[tid] = c;
    __syncthreads();
    for (int s = 1; s < 256; s <<= 1) {
        int v = (tid >= s) ? tmp[tid - s] : 0;
        __syncthreads();
        tmp[tid] += v;
        __syncthreads();
    }
    if (tid < MAXINS) { off[tid] = tmp[tid] - c; off_run[tid] = tmp[tid] - c; }
    if (tid == 0) off[MAXINS] = STRIPE;
    __syncthreads();

    // ---- scatter local pixel ids into m-sorted order ----
    for (int p = tid; p < STRIPE; p += 256) {
        int slot = atomicAdd(&off_run[mloc[p]], 1);   // ds_add_rtn_u32
        sorted[slot] = (unsigned short)p;
    }
    __syncthreads();

    // ---- phase 2: per-(m,e4) register accumulation, no atomics ----
    // item = m*9 + e4; lanes 0..8 of an item-group read the same pixel's
    // contiguous 144B. 8 items/thread unrolled -> 8-wide load ILP.
    const float4* src = compsrc + (size_t)(b * PIX + pix0) * CE4;
    float4 acc[ITEMS];
    int base_[ITEMS], len_[ITEMS], e4_[ITEMS];
    int maxlen = 0;
    #pragma unroll
    for (int j = 0; j < ITEMS; ++j) {
        const int item = tid + 256 * j;
        acc[j] = make_float4(0.f, 0.f, 0.f, 0.f);
        if (item < BATCH_F4) {
            const int m  = item / CE4;
            e4_[j]   = item - m * CE4;
            base_[j] = off[m];
            len_[j]  = off[m + 1] - off[m];
            maxlen   = len_[j] > maxlen ? len_[j] : maxlen;
        } else { base_[j] = 0; len_[j] = 0; e4_[j] = 0; }
    }
    for (int i = 0; i < maxlen; ++i) {
        #pragma unroll
        for (int j = 0; j < ITEMS; ++j) {
            if (i < len_[j]) {
                const int pl = sorted[base_[j] + i];     // LDS bcast in group
                float4 v = src[(size_t)pl * CE4 + e4_[j]];
                acc[j].x += v.x; acc[j].y += v.y; acc[j].z += v.z; acc[j].w += v.w;
            }
        }
    }

    // ---- store full partial (zeros included): every byte overwritten ----
    float4* p = partials + (size_t)blockIdx.x * BATCH_F4;
    #pragma unroll
    for (int j = 0; j < ITEMS; ++j) {
        const int item = tid + 256 * j;
        if (item < BATCH_F4) p[item] = acc[j];           // coalesced
    }
}

// comp[t4] = sel gather + sum over the BPB partial slots of batch b
__global__ void reduce_priv_kernel(const float4* __restrict__ partials,
                                   const int* __restrict__ batchidx,
                                   const float4* __restrict__ selsrc,
                                   float4* __restrict__ comp) {
    const int t = blockIdx.x * blockDim.x + threadIdx.x;   // over 7200 float4
    if (t >= COMP_FLOATS / 4) return;
    const int e4 = t % CE4;
    const int bm = t / CE4;                    // b*MAXINS + m
    const int b  = t / BATCH_F4;
    const int j  = t - b * BATCH_F4;           // == (bm%MAXINS)*9 + e4
    const int c  = batchidx[bm];
    float4 acc = selsrc[((size_t)bm * CAND + c) * CE4 + e4];
    const float4* p = partials + (size_t)b * BPB * BATCH_F4 + j;
    #pragma unroll 8
    for (int s = 0; s < BPB; ++s) {
        float4 v = p[(size_t)s * BATCH_F4];    // independent loads -> ILP
        acc.x += v.x; acc.y += v.y; acc.z += v.z; acc.w += v.w;
    }
    comp[t] = acc;
}

// ============ fallback (tiny ws): direct atomics =========================

__global__ void init_sel_kernel(const int* __restrict__ batchidx,
                                const float4* __restrict__ selsrc,
                                float4* __restrict__ comp) {
    unsigned t = blockIdx.x * blockDim.x + threadIdx.x;   // 7200
    if (t >= BZ * MAXINS * CE4) return;
    unsigned e4 = t % CE4;
    unsigned bm = t / CE4;
    int c = batchidx[bm];
    comp[bm * CE4 + e4] = selsrc[(bm * CAND + (unsigned)c) * CE4 + e4];
}

__global__ void compress_direct_kernel(const int* __restrict__ inst,
                                       const float4* __restrict__ compsrc,
                                       float* __restrict__ comp) {
    const unsigned total = BZ * PIX * CE4;
    for (unsigned t = blockIdx.x * blockDim.x + threadIdx.x; t < total;
         t += gridDim.x * blockDim.x) {
        unsigned e4 = t % CE4;
        unsigned pix = t / CE4;
        unsigned b = pix / PIX;
        int m = inst[pix];
        float4 v = compsrc[t];
        float* dst = comp + ((unsigned)(b * MAXINS + m)) * CE + e4 * 4;
        atomicAdd(dst + 0, v.x);
        atomicAdd(dst + 1, v.y);
        atomicAdd(dst + 2, v.z);
        atomicAdd(dst + 3, v.w);
    }
}

// ============ K3: inflate ================================================

__global__ void inflate_kernel(const int* __restrict__ inst,
                               const float4* __restrict__ comp,
                               float4* __restrict__ out) {
    const unsigned total = BZ * PIX * CE4;
    for (unsigned t = blockIdx.x * blockDim.x + threadIdx.x; t < total;
         t += gridDim.x * blockDim.x) {
        unsigned e4 = t % CE4;
        unsigned pix = t / CE4;
        unsigned b = pix / PIX;
        int m = inst[pix];
        out[t] = comp[((unsigned)(b * MAXINS + m)) * CE4 + e4];  // L2-hot gather
    }
}

extern "C" void kernel_launch(void* const* d_in, const int* in_sizes, int n_in,
                              void* d_out, int out_size, void* d_ws, size_t ws_size,
                              hipStream_t stream) {
    const int*    inst     = (const int*)d_in[0];      // (BZ,1,H,W) int32
    const float*  compsrc  = (const float*)d_in[1];    // (BZ,H,W,6,6) f32
    const int*    batchidx = (const int*)d_in[2];      // (BZ,MAXINS) int32
    const float*  selsrc   = (const float*)d_in[3];    // (BZ,MAXINS,CAND,6,6) f32
    float*        out      = (float*)d_out;            // (BZ,H,W,6,6) f32
    float*        comp     = (float*)d_ws;             // final comp: 115.2 KB @ ws[0]

    if (ws_size >= (size_t)COMP_BYTES + PART_BYTES) {
        // --- main path: counting-sort compress, no fp atomics, no zeroing ---
        float4* partials = (float4*)(comp + COMP_FLOATS);
        compress_sort_kernel<<<NBLK, 256, 0, stream>>>(inst, (const float4*)compsrc,
                                                       partials);
        reduce_priv_kernel<<<(COMP_FLOATS / 4 + 255) / 256, 256, 0, stream>>>(
            partials, batchidx, (const float4*)selsrc, (float4*)comp);
    } else {
        // --- fallback: direct atomics into comp ---
        const int total = BZ * MAXINS * CE4;
        init_sel_kernel<<<(total + 255) / 256, 256, 0, stream>>>(
            batchidx, (const float4*)selsrc, (float4*)comp);
        compress_direct_kernel<<<2048, 256, 0, stream>>>(inst, (const float4*)compsrc,
                                                         comp);
    }

    // K3: inflate comp back to per-pixel output
    inflate_kernel<<<2048, 256, 0, stream>>>(inst, (const float4*)comp, (float4*)out);
}

// Round 12
// 49.210 us; speedup vs baseline: 2.4802x; 1.1502x over previous
//
#include <hip/hip_runtime.h>

// Problem constants (from reference setup_inputs)
#define BZ 4
#define H 192
#define W 640
#define PIX (H * W)            // 122880 pixels per batch
#define MAXINS 200
#define CAND 16
#define CE 36                  // ch*cw
#define CE4 9                  // float4 groups per pixel
#define BATCH_FLOATS (MAXINS * CE)          // 7200 floats per batch
#define BATCH_F4     (BATCH_FLOATS / 4)     // 1800 float4 per batch
#define COMP_FLOATS (BZ * BATCH_FLOATS)     // 28800 floats
#define COMP_BYTES  (COMP_FLOATS * 4)       // 115200 bytes
#define BPB 192                             // blocks per batch
#define NBLK (BZ * BPB)                     // 768 compress blocks
#define STRIPE (PIX / BPB)                  // 640 contiguous pixels per block
#define TPB 512                             // threads per block (r11: 256 -> 512, 3x TLP)
#define ITEMS 4                             // ceil(1800/512) per-thread items
#define PART_BYTES ((size_t)NBLK * BATCH_FLOATS * 4)   // 22.1 MB

// ============ compress: block-local counting sort, NO fp atomics =========
// r11 measured: latency-bound (VALU 4.8%, HBM 19%, occ 24%). This round:
// 512-thread blocks (24 waves/CU) + software-pipelined phase-2 loop.

__global__ __launch_bounds__(TPB) void compress_sort_kernel(
        const int* __restrict__ inst,
        const float4* __restrict__ compsrc,
        float4* __restrict__ partials) {
    __shared__ unsigned char  mloc[STRIPE];     // per-pixel m (cached)
    __shared__ unsigned short sorted[STRIPE];   // local pixel ids, grouped by m
    __shared__ int cnt[MAXINS];
    __shared__ int off[MAXINS + 1];
    __shared__ int off_run[MAXINS];
    __shared__ int tmp[TPB];

    const int b    = blockIdx.x / BPB;
    const int blk  = blockIdx.x % BPB;
    const int tid  = threadIdx.x;
    const int pix0 = blk * STRIPE;

    if (tid < MAXINS) cnt[tid] = 0;
    __syncthreads();

    // ---- count pass: 640 int LDS atomics, cache m ----
    for (int p = tid; p < STRIPE; p += TPB) {
        int m = inst[b * PIX + pix0 + p];       // coalesced
        mloc[p] = (unsigned char)m;
        atomicAdd(&cnt[m], 1);                  // ds_add_u32
    }
    __syncthreads();

    // ---- exclusive scan cnt -> off (Hillis-Steele, TPB-wide, uniform syncs) ----
    int c = (tid < MAXINS) ? cnt[tid] : 0;
    tmp[tid] = c;
    __syncthreads();
    for (int s = 1; s < TPB; s <<= 1) {
        int v = (tid >= s) ? tmp[tid - s] : 0;
        __syncthreads();
        tmp[tid] += v;
        __syncthreads();
    }
    if (tid < MAXINS) { off[tid] = tmp[tid] - c; off_run[tid] = tmp[tid] - c; }
    if (tid == 0) off[MAXINS] = STRIPE;
    __syncthreads();

    // ---- scatter local pixel ids into m-sorted order ----
    for (int p = tid; p < STRIPE; p += TPB) {
        int slot = atomicAdd(&off_run[mloc[p]], 1);   // ds_add_rtn_u32
        sorted[slot] = (unsigned short)p;
    }
    __syncthreads();

    // ---- phase 2: per-(m,e4) register accumulation, software-pipelined ----
    // item = m*9 + e4; consecutive lanes of an item-group read the same
    // pixel's contiguous 144B. Prefetch next sorted[] index while this
    // iteration's global loads are in flight (break LDS->VMEM chain).
    const float4* src = compsrc + (size_t)(b * PIX + pix0) * CE4;
    float4 acc[ITEMS];
    int base_[ITEMS], len_[ITEMS], e4_[ITEMS], idx_[ITEMS];
    int maxlen = 0;
    #pragma unroll
    for (int j = 0; j < ITEMS; ++j) {
        const int item = tid + TPB * j;
        acc[j] = make_float4(0.f, 0.f, 0.f, 0.f);
        if (item < BATCH_F4) {
            const int m  = item / CE4;
            e4_[j]   = item - m * CE4;
            base_[j] = off[m];
            len_[j]  = off[m + 1] - off[m];
            maxlen   = len_[j] > maxlen ? len_[j] : maxlen;
        } else { base_[j] = 0; len_[j] = 0; e4_[j] = 0; }
        idx_[j] = (0 < len_[j]) ? (int)sorted[base_[j]] : 0;   // prefetch i=0
    }
    for (int i = 0; i < maxlen; ++i) {
        float4 v[ITEMS];
        #pragma unroll
        for (int j = 0; j < ITEMS; ++j)
            if (i < len_[j]) v[j] = src[(size_t)idx_[j] * CE4 + e4_[j]];  // VMEM issue
        #pragma unroll
        for (int j = 0; j < ITEMS; ++j)                        // LDS prefetch i+1
            idx_[j] = (i + 1 < len_[j]) ? (int)sorted[base_[j] + i + 1] : 0;
        #pragma unroll
        for (int j = 0; j < ITEMS; ++j)
            if (i < len_[j]) {
                acc[j].x += v[j].x; acc[j].y += v[j].y;
                acc[j].z += v[j].z; acc[j].w += v[j].w;
            }
    }

    // ---- store full partial (zeros included): every byte overwritten ----
    float4* p = partials + (size_t)blockIdx.x * BATCH_F4;
    #pragma unroll
    for (int j = 0; j < ITEMS; ++j) {
        const int item = tid + TPB * j;
        if (item < BATCH_F4) p[item] = acc[j];           // coalesced
    }
}

// comp[t4] = sel gather + sum over the BPB partial slots of batch b
__global__ void reduce_priv_kernel(const float4* __restrict__ partials,
                                   const int* __restrict__ batchidx,
                                   const float4* __restrict__ selsrc,
                                   float4* __restrict__ comp) {
    const int t = blockIdx.x * blockDim.x + threadIdx.x;   // over 7200 float4
    if (t >= COMP_FLOATS / 4) return;
    const int e4 = t % CE4;
    const int bm = t / CE4;                    // b*MAXINS + m
    const int b  = t / BATCH_F4;
    const int j  = t - b * BATCH_F4;           // == (bm%MAXINS)*9 + e4
    const int c  = batchidx[bm];
    float4 acc = selsrc[((size_t)bm * CAND + c) * CE4 + e4];
    const float4* p = partials + (size_t)b * BPB * BATCH_F4 + j;
    #pragma unroll 8
    for (int s = 0; s < BPB; ++s) {
        float4 v = p[(size_t)s * BATCH_F4];    // independent loads -> ILP
        acc.x += v.x; acc.y += v.y; acc.z += v.z; acc.w += v.w;
    }
    comp[t] = acc;
}

// ============ fallback (tiny ws): direct atomics =========================

__global__ void init_sel_kernel(const int* __restrict__ batchidx,
                                const float4* __restrict__ selsrc,
                                float4* __restrict__ comp) {
    unsigned t = blockIdx.x * blockDim.x + threadIdx.x;   // 7200
    if (t >= BZ * MAXINS * CE4) return;
    unsigned e4 = t % CE4;
    unsigned bm = t / CE4;
    int c = batchidx[bm];
    comp[bm * CE4 + e4] = selsrc[(bm * CAND + (unsigned)c) * CE4 + e4];
}

__global__ void compress_direct_kernel(const int* __restrict__ inst,
                                       const float4* __restrict__ compsrc,
                                       float* __restrict__ comp) {
    const unsigned total = BZ * PIX * CE4;
    for (unsigned t = blockIdx.x * blockDim.x + threadIdx.x; t < total;
         t += gridDim.x * blockDim.x) {
        unsigned e4 = t % CE4;
        unsigned pix = t / CE4;
        unsigned b = pix / PIX;
        int m = inst[pix];
        float4 v = compsrc[t];
        float* dst = comp + ((unsigned)(b * MAXINS + m)) * CE + e4 * 4;
        atomicAdd(dst + 0, v.x);
        atomicAdd(dst + 1, v.y);
        atomicAdd(dst + 2, v.z);
        atomicAdd(dst + 3, v.w);
    }
}

// ============ K3: inflate ================================================

__global__ void inflate_kernel(const int* __restrict__ inst,
                               const float4* __restrict__ comp,
                               float4* __restrict__ out) {
    const unsigned total = BZ * PIX * CE4;
    for (unsigned t = blockIdx.x * blockDim.x + threadIdx.x; t < total;
         t += gridDim.x * blockDim.x) {
        unsigned e4 = t % CE4;
        unsigned pix = t / CE4;
        unsigned b = pix / PIX;
        int m = inst[pix];
        out[t] = comp[((unsigned)(b * MAXINS + m)) * CE4 + e4];  // L2-hot gather
    }
}

extern "C" void kernel_launch(void* const* d_in, const int* in_sizes, int n_in,
                              void* d_out, int out_size, void* d_ws, size_t ws_size,
                              hipStream_t stream) {
    const int*    inst     = (const int*)d_in[0];      // (BZ,1,H,W) int32
    const float*  compsrc  = (const float*)d_in[1];    // (BZ,H,W,6,6) f32
    const int*    batchidx = (const int*)d_in[2];      // (BZ,MAXINS) int32
    const float*  selsrc   = (const float*)d_in[3];    // (BZ,MAXINS,CAND,6,6) f32
    float*        out      = (float*)d_out;            // (BZ,H,W,6,6) f32
    float*        comp     = (float*)d_ws;             // final comp: 115.2 KB @ ws[0]

    if (ws_size >= (size_t)COMP_BYTES + PART_BYTES) {
        // --- main path: counting-sort compress, no fp atomics, no zeroing ---
        float4* partials = (float4*)(comp + COMP_FLOATS);
        compress_sort_kernel<<<NBLK, TPB, 0, stream>>>(inst, (const float4*)compsrc,
                                                       partials);
        reduce_priv_kernel<<<(COMP_FLOATS / 4 + 255) / 256, 256, 0, stream>>>(
            partials, batchidx, (const float4*)selsrc, (float4*)comp);
    } else {
        // --- fallback: direct atomics into comp ---
        const int total = BZ * MAXINS * CE4;
        init_sel_kernel<<<(total + 255) / 256, 256, 0, stream>>>(
            batchidx, (const float4*)selsrc, (float4*)comp);
        compress_direct_kernel<<<2048, 256, 0, stream>>>(inst, (const float4*)compsrc,
                                                         comp);
    }

    // K3: inflate comp back to per-pixel output
    inflate_kernel<<<2048, 256, 0, stream>>>(inst, (const float4*)comp, (float4*)out);
}